// Round 2
// baseline (433.914 us; speedup 1.0000x reference)
//
#include <hip/hip_runtime.h>
#include <math.h>

#define TI 16          // i-rows per block
#define BLOCK 1024     // threads per block (16 waves)
#define DIM 16         // embedding dim (fixed by problem)
#define JSPLIT 2       // split j-range for occupancy

// Counting sort of idx (keys in [0,N)) -> perm (batch positions sorted by key),
// skey (sorted key values). One block, dynamic LDS = N ints.
__global__ __launch_bounds__(1024) void sort_kernel(
    const int* __restrict__ idx, int B, int N,
    int* __restrict__ perm, int* __restrict__ skey)
{
    extern __shared__ int hist[];        // N ints
    __shared__ int tsum[1024];
    const int tid = threadIdx.x;
    for (int b = tid; b < N; b += 1024) hist[b] = 0;
    __syncthreads();
    for (int j = tid; j < B; j += 1024) atomicAdd(&hist[idx[j]], 1);
    __syncthreads();
    const int PB = (N + 1023) >> 10;     // bins per thread (8 for N=8192)
    int local[8];
    int sum = 0;
    #pragma unroll
    for (int q = 0; q < 8; ++q) {
        if (q < PB) {
            int b = tid * PB + q;
            local[q] = sum;
            if (b < N) sum += hist[b];
        }
    }
    tsum[tid] = sum;
    __syncthreads();
    for (int off = 1; off < 1024; off <<= 1) {
        int v = (tid >= off) ? tsum[tid - off] : 0;
        __syncthreads();
        tsum[tid] += v;
        __syncthreads();
    }
    int excl = (tid == 0) ? 0 : tsum[tid - 1];
    #pragma unroll
    for (int q = 0; q < 8; ++q) {
        if (q < PB) {
            int b = tid * PB + q;
            if (b < N) hist[b] = excl + local[q];
        }
    }
    __syncthreads();
    for (int j = tid; j < B; j += 1024) {
        int k = idx[j];
        int pos = atomicAdd(&hist[k], 1);
        perm[pos] = j;
        skey[pos] = k;
    }
}

__global__ __launch_bounds__(BLOCK) void pair_kernel(
    const float* __restrict__ z, const float* __restrict__ W,
    const int* __restrict__ perm, const int* __restrict__ skey,
    int B, int N, double* __restrict__ ws)
{
    __shared__ float zi[TI][DIM];
    __shared__ float sqi_s[TI];
    __shared__ float rai_s[TI];
    __shared__ int   wrow_s[TI];      // W row = sorted key of the i-slot
    __shared__ int   pi_s[TI];        // batch position of the i-slot
    __shared__ double red[BLOCK / 64][4];

    const int tid = threadIdx.x;
    const int i0  = blockIdx.x * TI;

    if (tid < TI) {
        int p = perm[i0 + tid];
        pi_s[tid]   = p;
        wrow_s[tid] = skey[i0 + tid];
        float s = 0.f;
        #pragma unroll
        for (int k = 0; k < DIM; ++k) {
            float v = z[(size_t)p * DIM + k];
            zi[tid][k] = v;
            s = fmaf(v, v, s);
        }
        sqi_s[tid] = s;
        float sc = fminf(fmaxf(s, 0.f), 0.99999f);
        rai_s[tid] = 1.0f / (1.0f - sc);
    }
    __syncthreads();

    int wrow[TI], pis[TI];
    #pragma unroll
    for (int ii = 0; ii < TI; ++ii) { wrow[ii] = wrow_s[ii]; pis[ii] = pi_s[ii]; }

    double s_wd = 0.0, s_w = 0.0, s_rep = 0.0;
    long long cnt = 0;

    const int jchunk = B / JSPLIT;
    const int jbase  = blockIdx.y * jchunk;

    for (int sub = 0; sub < jchunk; sub += BLOCK) {
        const int jj = jbase + sub + tid;
        const int pj = perm[jj];          // batch position of this j
        const int kj = skey[jj];          // W column (sorted across lanes!)

        float zj[DIM];
        const float4* zp = reinterpret_cast<const float4*>(z + (size_t)pj * DIM);
        #pragma unroll
        for (int q = 0; q < 4; ++q) {
            float4 v = zp[q];
            zj[4*q+0] = v.x; zj[4*q+1] = v.y; zj[4*q+2] = v.z; zj[4*q+3] = v.w;
        }
        float sj = 0.f;
        #pragma unroll
        for (int k = 0; k < DIM; ++k) sj = fmaf(zj[k], zj[k], sj);
        float scj = fminf(fmaxf(sj, 0.f), 0.99999f);
        float rj  = 1.0f / (1.0f - scj);

        // 16 gathers; lanes hit near-consecutive columns -> coalesced lines
        float wv[TI];
        #pragma unroll
        for (int ii = 0; ii < TI; ++ii)
            wv[ii] = W[(size_t)wrow[ii] * (size_t)N + (size_t)kj];

        #pragma unroll
        for (int ii = 0; ii < TI; ++ii) {
            float dot = 0.f;
            #pragma unroll
            for (int k = 0; k < DIM; ++k) dot = fmaf(zi[ii][k], zj[k], dot);
            float sqd = fmaxf(sqi_s[ii] + sj - 2.0f * dot, 0.0f);
            float x = fmaf(sqd * rai_s[ii] * rj, 2.0f, 1.0f);
            float t = sqrtf(fmaxf(fmaf(x, x, -1.0f), 1e-10f));
            // d = log(x+t); exp(-d) = 1/(x+t) = x-t exactly (since (x+t)(x-t)=1)
            bool diag = (pis[ii] == pj);
            float w = wv[ii];
            if (!diag) {
                if (w != 0.0f) {
                    s_wd += (double)(w * logf(x + t));
                    s_w  += (double)w;
                } else {
                    s_rep += (double)(x - t);
                    cnt++;
                }
            }
        }
    }

    double vals[4] = { s_wd, s_w, s_rep, (double)cnt };
    #pragma unroll
    for (int c = 0; c < 4; ++c) {
        double v = vals[c];
        for (int off = 32; off > 0; off >>= 1) v += __shfl_down(v, off);
        vals[c] = v;
    }
    const int wid = tid >> 6, lane = tid & 63;
    if (lane == 0) {
        #pragma unroll
        for (int c = 0; c < 4; ++c) red[wid][c] = vals[c];
    }
    __syncthreads();
    if (tid == 0) {
        double tot[4] = {0.0, 0.0, 0.0, 0.0};
        for (int wgt = 0; wgt < BLOCK / 64; ++wgt)
            for (int c = 0; c < 4; ++c) tot[c] += red[wgt][c];
        for (int c = 0; c < 4; ++c) atomicAdd(&ws[c], tot[c]);
    }
}

__global__ void finish_kernel(const double* __restrict__ ws, float* __restrict__ out)
{
    double la = ws[0] / (ws[1] + 1e-8);
    double lr = ws[2] / (ws[3] + 1e-8);
    out[0] = (float)(la + lr);
}

extern "C" void kernel_launch(void* const* d_in, const int* in_sizes, int n_in,
                              void* d_out, int out_size, void* d_ws, size_t ws_size,
                              hipStream_t stream)
{
    const float* z  = (const float*)d_in[0];
    const float* W  = (const float*)d_in[1];
    const int* idx  = (const int*)d_in[2];
    const int B = in_sizes[2];                       // 4096
    int N = 1;
    while ((long long)(N + 1) * (N + 1) <= (long long)in_sizes[1]) ++N;

    double* ws = (double*)d_ws;
    int* perm = (int*)(ws + 4);
    int* skey = perm + B;
    hipMemsetAsync(ws, 0, 4 * sizeof(double), stream);

    sort_kernel<<<1, 1024, (size_t)N * sizeof(int), stream>>>(idx, B, N, perm, skey);

    dim3 grid(B / TI, JSPLIT);
    pair_kernel<<<grid, BLOCK, 0, stream>>>(z, W, perm, skey, B, N, ws);
    finish_kernel<<<1, 1, 0, stream>>>(ws, (float*)d_out);
}

// Round 3
// 90.950 us; speedup vs baseline: 4.7709x; 4.7709x over previous
//
#include <hip/hip_runtime.h>
#include <math.h>

#define TI 16          // i-rows per block (= waves per block)
#define BLOCK 1024     // threads per block
#define DIM 16         // embedding dim
#define JSPLIT 4       // j-chunks
// JC = B/JSPLIT = 1024 for B=4096

// Counting sort of idx (keys in [0,N)) -> perm (batch positions sorted by key),
// skey (sorted keys), colend (cumulative end offset per key = CSR row ends).
__global__ __launch_bounds__(1024) void sort_kernel(
    const int* __restrict__ idx, int B, int N,
    int* __restrict__ perm, int* __restrict__ skey, int* __restrict__ colend)
{
    extern __shared__ int hist[];        // N ints
    __shared__ int tsum[1024];
    const int tid = threadIdx.x;
    for (int b = tid; b < N; b += 1024) hist[b] = 0;
    __syncthreads();
    for (int j = tid; j < B; j += 1024) atomicAdd(&hist[idx[j]], 1);
    __syncthreads();
    const int PB = (N + 1023) >> 10;     // bins per thread
    int local[8];
    int sum = 0;
    #pragma unroll
    for (int q = 0; q < 8; ++q) {
        if (q < PB) {
            int b = tid * PB + q;
            local[q] = sum;
            if (b < N) sum += hist[b];
        }
    }
    tsum[tid] = sum;
    __syncthreads();
    for (int off = 1; off < 1024; off <<= 1) {
        int v = (tid >= off) ? tsum[tid - off] : 0;
        __syncthreads();
        tsum[tid] += v;
        __syncthreads();
    }
    int excl = (tid == 0) ? 0 : tsum[tid - 1];
    #pragma unroll
    for (int q = 0; q < 8; ++q) {
        if (q < PB) {
            int b = tid * PB + q;
            if (b < N) hist[b] = excl + local[q];
        }
    }
    __syncthreads();
    for (int j = tid; j < B; j += 1024) {
        int k = idx[j];
        int pos = atomicAdd(&hist[k], 1);
        perm[pos] = j;
        skey[pos] = k;
    }
    __syncthreads();
    for (int b = tid; b < N; b += 1024) colend[b] = hist[b];  // = end offsets
}

// Permute z into sorted-rank order; precompute norms.
__global__ __launch_bounds__(256) void prep_kernel(
    const float* __restrict__ z, const int* __restrict__ perm, int B,
    float* __restrict__ zs, float* __restrict__ sqs, float* __restrict__ ras)
{
    int r = blockIdx.x * 256 + threadIdx.x;
    if (r >= B) return;
    int p = perm[r];
    const float4* src = reinterpret_cast<const float4*>(z + (size_t)p * DIM);
    float4* dst = reinterpret_cast<float4*>(zs + (size_t)r * DIM);
    float s = 0.f;
    #pragma unroll
    for (int q = 0; q < 4; ++q) {
        float4 v = src[q];
        dst[q] = v;
        s = fmaf(v.x, v.x, s); s = fmaf(v.y, v.y, s);
        s = fmaf(v.z, v.z, s); s = fmaf(v.w, v.w, s);
    }
    sqs[r] = s;
    float sc = fminf(fmaxf(s, 0.f), 0.99999f);
    ras[r] = 1.0f / (1.0f - sc);
}

__global__ __launch_bounds__(BLOCK) void pair_kernel(
    const float* __restrict__ W, const int* __restrict__ skey,
    const int* __restrict__ colend,
    const float* __restrict__ zs, const float* __restrict__ sqs,
    const float* __restrict__ ras,
    int B, int N, int JC, double* __restrict__ partial)
{
    __shared__ float wlds[TI][1024];   // 64 KB: W values by (row-slot, local j-rank)
    __shared__ float zi[TI][DIM];
    __shared__ float sqi[TI], rai[TI];
    __shared__ double red[TI][4];

    const int tid  = threadIdx.x;
    const int wid  = tid >> 6;
    const int lane = tid & 63;
    const int i0   = blockIdx.x * TI;
    const int jr0  = blockIdx.y * JC;

    // stage i-rows
    if (tid < TI * DIM) {
        int ii = tid >> 4, k = tid & 15;
        zi[ii][k] = zs[(size_t)(i0 + ii) * DIM + k];
    }
    if (tid < TI) { sqi[tid] = sqs[i0 + tid]; rai[tid] = ras[i0 + tid]; }

    // dense W row read + scatter into wlds (wave w owns row-slot w)
    const int row  = skey[i0 + wid];               // wave-uniform
    const int cmin = skey[jr0];
    const int cmax = skey[jr0 + JC - 1];
    const float* Wrow = W + (size_t)row * (size_t)N;
    for (int c = cmin + lane; c <= cmax; c += 64) {
        float wv = Wrow[c];                         // stride-1 across lanes
        int e0 = (c == 0) ? 0 : colend[c - 1];
        int e1 = colend[c];
        int r0 = e0 > jr0 ? e0 : jr0;
        int r1 = e1 < jr0 + JC ? e1 : jr0 + JC;
        for (int r = r0; r < r1; ++r) wlds[wid][r - jr0] = wv;
    }
    __syncthreads();

    // pair compute: this thread owns sorted j-rank jj
    const int jj = jr0 + tid;
    float zj[DIM];
    const float4* zp = reinterpret_cast<const float4*>(zs + (size_t)jj * DIM);
    #pragma unroll
    for (int q = 0; q < 4; ++q) {
        float4 v = zp[q];
        zj[4*q+0] = v.x; zj[4*q+1] = v.y; zj[4*q+2] = v.z; zj[4*q+3] = v.w;
    }
    const float sqj = sqs[jj];
    const float raj = ras[jj];

    float a_wd = 0.f, a_w = 0.f, a_rep = 0.f;
    int a_cnt = 0;
    #pragma unroll
    for (int ii = 0; ii < TI; ++ii) {
        float w = wlds[ii][tid];
        float dot = 0.f;
        #pragma unroll
        for (int k = 0; k < DIM; ++k) dot = fmaf(zi[ii][k], zj[k], dot);
        float sqd = fmaxf(sqi[ii] + sqj - 2.0f * dot, 0.0f);
        float x = fmaf(sqd * rai[ii] * raj, 2.0f, 1.0f);
        float t = sqrtf(fmaxf(fmaf(x, x, -1.0f), 1e-10f));
        // d = log(x+t); exp(-d) = 1/(x+t) = x - t
        if ((i0 + ii) != jj) {
            if (w != 0.0f) {
                a_wd += w * logf(x + t);
                a_w  += w;
            } else {
                a_rep += x - t;
                a_cnt++;
            }
        }
    }

    double vals[4] = { (double)a_wd, (double)a_w, (double)a_rep, (double)a_cnt };
    #pragma unroll
    for (int c = 0; c < 4; ++c) {
        double v = vals[c];
        for (int off = 32; off > 0; off >>= 1) v += __shfl_down(v, off);
        vals[c] = v;
    }
    if (lane == 0) {
        #pragma unroll
        for (int c = 0; c < 4; ++c) red[wid][c] = vals[c];
    }
    __syncthreads();
    if (tid == 0) {
        double tot[4] = {0.0, 0.0, 0.0, 0.0};
        for (int wgt = 0; wgt < TI; ++wgt)
            for (int c = 0; c < 4; ++c) tot[c] += red[wgt][c];
        size_t bid = (size_t)blockIdx.y * gridDim.x + blockIdx.x;
        #pragma unroll
        for (int c = 0; c < 4; ++c) partial[bid * 4 + c] = tot[c];
    }
}

__global__ __launch_bounds__(1024) void finish_kernel(
    const double* __restrict__ partial, int nblocks, float* __restrict__ out)
{
    __shared__ double red[16][4];
    const int tid = threadIdx.x, wid = tid >> 6, lane = tid & 63;
    double vals[4] = {0.0, 0.0, 0.0, 0.0};
    for (int b = tid; b < nblocks; b += 1024)
        for (int c = 0; c < 4; ++c) vals[c] += partial[(size_t)b * 4 + c];
    #pragma unroll
    for (int c = 0; c < 4; ++c) {
        double v = vals[c];
        for (int off = 32; off > 0; off >>= 1) v += __shfl_down(v, off);
        vals[c] = v;
    }
    if (lane == 0)
        for (int c = 0; c < 4; ++c) red[wid][c] = vals[c];
    __syncthreads();
    if (tid == 0) {
        double tot[4] = {0.0, 0.0, 0.0, 0.0};
        for (int wgt = 0; wgt < 16; ++wgt)
            for (int c = 0; c < 4; ++c) tot[c] += red[wgt][c];
        double la = tot[0] / (tot[1] + 1e-8);
        double lr = tot[2] / (tot[3] + 1e-8);
        out[0] = (float)(la + lr);
    }
}

extern "C" void kernel_launch(void* const* d_in, const int* in_sizes, int n_in,
                              void* d_out, int out_size, void* d_ws, size_t ws_size,
                              hipStream_t stream)
{
    const float* z  = (const float*)d_in[0];
    const float* W  = (const float*)d_in[1];
    const int* idx  = (const int*)d_in[2];
    const int B = in_sizes[2];                       // 4096
    int N = 1;
    while ((long long)(N + 1) * (N + 1) <= (long long)in_sizes[1]) ++N;

    const int JC = B / JSPLIT;
    const int nblocks = (B / TI) * JSPLIT;

    // workspace layout
    double* partial = (double*)d_ws;                 // nblocks*4 doubles
    int* perm   = (int*)(partial + (size_t)nblocks * 4);
    int* skey   = perm + B;
    int* colend = skey + B;
    float* zs   = (float*)(colend + N);              // B*DIM floats
    float* sqs  = zs + (size_t)B * DIM;
    float* ras  = sqs + B;

    sort_kernel<<<1, 1024, (size_t)N * sizeof(int), stream>>>(idx, B, N, perm, skey, colend);
    prep_kernel<<<(B + 255) / 256, 256, 0, stream>>>(z, perm, B, zs, sqs, ras);

    dim3 grid(B / TI, JSPLIT);
    pair_kernel<<<grid, BLOCK, 0, stream>>>(W, skey, colend, zs, sqs, ras,
                                            B, N, JC, partial);
    finish_kernel<<<1, 1024, 0, stream>>>(partial, nblocks, (float*)d_out);
}

// Round 4
// 77.856 us; speedup vs baseline: 5.5733x; 1.1682x over previous
//
#include <hip/hip_runtime.h>
#include <math.h>

#define TI 16          // i-rows per block (= waves per block)
#define BLOCK 1024     // threads per block
#define DIM 16         // embedding dim
#define JSPLIT 4       // j-chunks; JC = B/JSPLIT = 1024

// Counting sort of idx (keys in [0,N)) -> perm (positions sorted by key),
// skey (sorted keys), colstart/colend (CSR offsets per key).
__global__ __launch_bounds__(1024) void sort_kernel(
    const int* __restrict__ idx, int B, int N,
    int* __restrict__ perm, int* __restrict__ skey,
    int* __restrict__ colstart, int* __restrict__ colend)
{
    extern __shared__ int hist[];        // N ints
    __shared__ int tsum[1024];
    const int tid = threadIdx.x;
    for (int b = tid; b < N; b += 1024) hist[b] = 0;
    __syncthreads();
    for (int j = tid; j < B; j += 1024) atomicAdd(&hist[idx[j]], 1);
    __syncthreads();
    const int PB = (N + 1023) >> 10;     // bins per thread
    int local[8];
    int sum = 0;
    #pragma unroll
    for (int q = 0; q < 8; ++q) {
        if (q < PB) {
            int b = tid * PB + q;
            local[q] = sum;
            if (b < N) sum += hist[b];
        }
    }
    tsum[tid] = sum;
    __syncthreads();
    for (int off = 1; off < 1024; off <<= 1) {
        int v = (tid >= off) ? tsum[tid - off] : 0;
        __syncthreads();
        tsum[tid] += v;
        __syncthreads();
    }
    int excl = (tid == 0) ? 0 : tsum[tid - 1];
    #pragma unroll
    for (int q = 0; q < 8; ++q) {
        if (q < PB) {
            int b = tid * PB + q;
            if (b < N) hist[b] = excl + local[q];
        }
    }
    __syncthreads();
    for (int b = tid; b < N; b += 1024) colstart[b] = hist[b];  // start offsets
    __syncthreads();
    for (int j = tid; j < B; j += 1024) {
        int k = idx[j];
        int pos = atomicAdd(&hist[k], 1);
        perm[pos] = j;
        skey[pos] = k;
    }
    __syncthreads();
    for (int b = tid; b < N; b += 1024) colend[b] = hist[b];    // end offsets
}

// Permute z into sorted-rank order; precompute norms.
__global__ __launch_bounds__(256) void prep_kernel(
    const float* __restrict__ z, const int* __restrict__ perm, int B,
    float* __restrict__ zs, float* __restrict__ sqs, float* __restrict__ ras)
{
    int r = blockIdx.x * 256 + threadIdx.x;
    if (r >= B) return;
    int p = perm[r];
    const float4* src = reinterpret_cast<const float4*>(z + (size_t)p * DIM);
    float4* dst = reinterpret_cast<float4*>(zs + (size_t)r * DIM);
    float s = 0.f;
    #pragma unroll
    for (int q = 0; q < 4; ++q) {
        float4 v = src[q];
        dst[q] = v;
        s = fmaf(v.x, v.x, s); s = fmaf(v.y, v.y, s);
        s = fmaf(v.z, v.z, s); s = fmaf(v.w, v.w, s);
    }
    sqs[r] = s;
    float sc = fminf(fmaxf(s, 0.f), 0.99999f);
    ras[r] = 1.0f / (1.0f - sc);
}

__global__ __launch_bounds__(BLOCK) void pair_kernel(
    const float* __restrict__ W, const int* __restrict__ skey,
    const int* __restrict__ colstart, const int* __restrict__ colend,
    const float* __restrict__ zs, const float* __restrict__ sqs,
    const float* __restrict__ ras,
    int B, int N, int JC, double* __restrict__ partial)
{
    __shared__ float wlds[TI][1024];   // 64 KB: W values by (row-slot, local j-rank)
    __shared__ float zi[TI][DIM];
    __shared__ float sqi[TI], rai[TI];
    __shared__ double red[TI][4];

    const int tid  = threadIdx.x;
    const int wid  = tid >> 6;
    const int lane = tid & 63;
    const int i0   = blockIdx.x * TI;
    const int jr0  = blockIdx.y * JC;
    const int jr1  = jr0 + JC;

    if (tid < TI * DIM) {
        int ii = tid >> 4, k = tid & 15;
        zi[ii][k] = zs[(size_t)(i0 + ii) * DIM + k];
    }
    if (tid < TI) { sqi[tid] = sqs[i0 + tid]; rai[tid] = ras[i0 + tid]; }

    // dense, vectorized W-row read + scatter into wlds (wave w owns row-slot w)
    const int row  = skey[i0 + wid];                 // wave-uniform
    const int cmin = skey[jr0] & ~3;                 // align down for float4/int4
    const int cmax = skey[jr1 - 1];
    const float* Wrow = W + (size_t)row * (size_t)N;
    for (int c = cmin + lane * 4; c <= cmax; c += 64 * 4) {
        float4 wv = *reinterpret_cast<const float4*>(Wrow + c);
        int4  s4  = *reinterpret_cast<const int4*>(colstart + c);
        int4  e4  = *reinterpret_cast<const int4*>(colend + c);
        float wa[4] = { wv.x, wv.y, wv.z, wv.w };
        int   sa[4] = { s4.x, s4.y, s4.z, s4.w };
        int   ea[4] = { e4.x, e4.y, e4.z, e4.w };
        #pragma unroll
        for (int q = 0; q < 4; ++q) {
            int r0 = sa[q] > jr0 ? sa[q] : jr0;
            int r1 = ea[q] < jr1 ? ea[q] : jr1;
            for (int r = r0; r < r1; ++r) wlds[wid][r - jr0] = wa[q];
        }
    }
    __syncthreads();

    // pair compute: this thread owns sorted j-rank jj (branchless)
    const int jj = jr0 + tid;
    float zj[DIM];
    const float4* zp = reinterpret_cast<const float4*>(zs + (size_t)jj * DIM);
    #pragma unroll
    for (int q = 0; q < 4; ++q) {
        float4 v = zp[q];
        zj[4*q+0] = v.x; zj[4*q+1] = v.y; zj[4*q+2] = v.z; zj[4*q+3] = v.w;
    }
    const float sqj = sqs[jj];
    const float raj = ras[jj];

    float a_wd = 0.f, a_w = 0.f, a_rep = 0.f;
    int a_cnt = 0;
    #pragma unroll
    for (int ii = 0; ii < TI; ++ii) {
        float w = wlds[ii][tid];
        bool diag = ((i0 + ii) == jj);
        float dot = 0.f;
        #pragma unroll
        for (int k = 0; k < DIM; ++k) dot = fmaf(zi[ii][k], zj[k], dot);
        float sqd = fmaxf(sqi[ii] + sqj - 2.0f * dot, 0.0f);
        float x = fmaf(sqd * rai[ii] * raj, 2.0f, 1.0f);
        float t = __builtin_amdgcn_sqrtf(fmaxf(fmaf(x, x, -1.0f), 1e-10f));
        float d = __logf(x + t);            // v_log_f32-based, ~1e-7 rel err
        if (diag) w = 0.0f;                 // attract: w*d adds 0 on diag
        a_wd += w * d;
        a_w  += w;
        bool rep = (w == 0.0f) && !diag;    // repel: exp(-d) = 1/(x+t) = x - t
        a_rep += rep ? (x - t) : 0.0f;
        a_cnt += rep ? 1 : 0;
    }

    double vals[4] = { (double)a_wd, (double)a_w, (double)a_rep, (double)a_cnt };
    #pragma unroll
    for (int c = 0; c < 4; ++c) {
        double v = vals[c];
        for (int off = 32; off > 0; off >>= 1) v += __shfl_down(v, off);
        vals[c] = v;
    }
    if (lane == 0) {
        #pragma unroll
        for (int c = 0; c < 4; ++c) red[wid][c] = vals[c];
    }
    __syncthreads();
    if (tid == 0) {
        double tot[4] = {0.0, 0.0, 0.0, 0.0};
        for (int wgt = 0; wgt < TI; ++wgt)
            for (int c = 0; c < 4; ++c) tot[c] += red[wgt][c];
        size_t bid = (size_t)blockIdx.y * gridDim.x + blockIdx.x;
        #pragma unroll
        for (int c = 0; c < 4; ++c) partial[bid * 4 + c] = tot[c];
    }
}

__global__ __launch_bounds__(1024) void finish_kernel(
    const double* __restrict__ partial, int nblocks, float* __restrict__ out)
{
    __shared__ double red[16][4];
    const int tid = threadIdx.x, wid = tid >> 6, lane = tid & 63;
    double vals[4] = {0.0, 0.0, 0.0, 0.0};
    for (int b = tid; b < nblocks; b += 1024)
        for (int c = 0; c < 4; ++c) vals[c] += partial[(size_t)b * 4 + c];
    #pragma unroll
    for (int c = 0; c < 4; ++c) {
        double v = vals[c];
        for (int off = 32; off > 0; off >>= 1) v += __shfl_down(v, off);
        vals[c] = v;
    }
    if (lane == 0)
        for (int c = 0; c < 4; ++c) red[wid][c] = vals[c];
    __syncthreads();
    if (tid == 0) {
        double tot[4] = {0.0, 0.0, 0.0, 0.0};
        for (int wgt = 0; wgt < 16; ++wgt)
            for (int c = 0; c < 4; ++c) tot[c] += red[wgt][c];
        double la = tot[0] / (tot[1] + 1e-8);
        double lr = tot[2] / (tot[3] + 1e-8);
        out[0] = (float)(la + lr);
    }
}

extern "C" void kernel_launch(void* const* d_in, const int* in_sizes, int n_in,
                              void* d_out, int out_size, void* d_ws, size_t ws_size,
                              hipStream_t stream)
{
    const float* z  = (const float*)d_in[0];
    const float* W  = (const float*)d_in[1];
    const int* idx  = (const int*)d_in[2];
    const int B = in_sizes[2];                       // 4096
    int N = 1;
    while ((long long)(N + 1) * (N + 1) <= (long long)in_sizes[1]) ++N;

    const int JC = B / JSPLIT;
    const int nblocks = (B / TI) * JSPLIT;

    // workspace layout
    double* partial = (double*)d_ws;                 // nblocks*4 doubles
    int* perm     = (int*)(partial + (size_t)nblocks * 4);
    int* skey     = perm + B;
    int* colstart = skey + B;
    int* colend   = colstart + N;
    float* zs     = (float*)(colend + N);            // B*DIM floats
    float* sqs    = zs + (size_t)B * DIM;
    float* ras    = sqs + B;

    sort_kernel<<<1, 1024, (size_t)N * sizeof(int), stream>>>(
        idx, B, N, perm, skey, colstart, colend);
    prep_kernel<<<(B + 255) / 256, 256, 0, stream>>>(z, perm, B, zs, sqs, ras);

    dim3 grid(B / TI, JSPLIT);
    pair_kernel<<<grid, BLOCK, 0, stream>>>(W, skey, colstart, colend,
                                            zs, sqs, ras, B, N, JC, partial);
    finish_kernel<<<1, 1024, 0, stream>>>(partial, nblocks, (float*)d_out);
}